// Round 10
// baseline (239.050 us; speedup 1.0000x reference)
//
#include <hip/hip_runtime.h>
#include <hip/hip_bf16.h>

#define T 2048
#define H 1024
#define IDIM 512
#define E 16
#define TOPK 4
#define NPAIR (T * TOPK)

typedef short bf16x8 __attribute__((ext_vector_type(8)));
typedef float f32x4 __attribute__((ext_vector_type(4)));
typedef unsigned short u16x8 __attribute__((ext_vector_type(8)));

static __device__ __forceinline__ unsigned short f2bf(float f) {
    union { float f; unsigned int u; } v; v.f = f;
    unsigned int r = (v.u + 0x7FFFu + ((v.u >> 16) & 1u)) >> 16;  // RNE
    return (unsigned short)r;
}
static __device__ __forceinline__ float bf2f(unsigned short s) {
    union { unsigned int u; float f; } v; v.u = ((unsigned int)s) << 16;
    return v.f;
}

static __device__ __forceinline__ void async_ld16(const unsigned short* g, unsigned short* l) {
    __builtin_amdgcn_global_load_lds((const __attribute__((address_space(1))) void*)g,
                                     (__attribute__((address_space(3))) void*)l, 16, 0, 0);
}

// ---------------- fp32 -> bf16 weights: 16B-wide stores ----------------
__global__ __launch_bounds__(256) void cvt3_kernel(
    const float* __restrict__ w1, const float* __restrict__ w3, const float* __restrict__ w2,
    unsigned short* __restrict__ d1, unsigned short* __restrict__ d3, unsigned short* __restrict__ d2)
{
    const int n8 = (E * IDIM * H) / 8;      // per-region float8 count (1M)
    int region = blockIdx.x >> 11;          // 3 regions x 2048 blocks
    int bid = blockIdx.x & 2047;
    const float* src = (region == 0) ? w1 : (region == 1) ? w3 : w2;
    unsigned short* dst = (region == 0) ? d1 : (region == 1) ? d3 : d2;
    int i = bid * 256 + threadIdx.x;
    const int stride = 2048 * 256;
#pragma unroll 2
    for (; i < n8; i += stride) {
        float4 a = ((const float4*)src)[2 * i];
        float4 b = ((const float4*)src)[2 * i + 1];
        u16x8 o;
        o[0] = f2bf(a.x); o[1] = f2bf(a.y); o[2] = f2bf(a.z); o[3] = f2bf(a.w);
        o[4] = f2bf(b.x); o[5] = f2bf(b.y); o[6] = f2bf(b.z); o[7] = f2bf(b.w);
        ((u16x8*)dst)[i] = o;
    }
}

// ---------------- Router (fp32 exact) + fused x->bf16 + zero(out) ----------------
// NO global histogram atomics (R4: 8192 device atomics to one line = ~100us).
// Also zeroes this block's 4 rows of `out` (replay-safe init for gemm_b atomics).
__global__ __launch_bounds__(256) void router_kernel(
    const float* __restrict__ x, const float* __restrict__ gw,
    int* __restrict__ topk_idx, float* __restrict__ topk_w,
    unsigned short* __restrict__ xb, float* __restrict__ out)
{
    int tok = blockIdx.x * 4 + (threadIdx.x >> 6);
    int lane = threadIdx.x & 63;
    if (tok >= T) return;
    // zero own output rows (in flight during the dot-products below)
    {
        float4 z = make_float4(0.f, 0.f, 0.f, 0.f);
        float4* orow = (float4*)(out + (size_t)tok * H);
#pragma unroll
        for (int j = 0; j < 4; ++j) orow[lane + j * 64] = z;
    }
    const float4* xt4 = (const float4*)(x + (size_t)tok * H);
    float4 xr[4];
#pragma unroll
    for (int j = 0; j < 4; ++j) xr[j] = xt4[lane + j * 64];
    ushort4* xbt = (ushort4*)(xb + (size_t)tok * H);
#pragma unroll
    for (int j = 0; j < 4; ++j) {
        ushort4 o;
        o.x = f2bf(xr[j].x); o.y = f2bf(xr[j].y);
        o.z = f2bf(xr[j].z); o.w = f2bf(xr[j].w);
        xbt[lane + j * 64] = o;
    }
    float logits[E];
#pragma unroll
    for (int e = 0; e < E; ++e) {
        const float4* ge4 = (const float4*)(gw + (size_t)e * H);
        float acc = 0.f;
#pragma unroll
        for (int j = 0; j < 4; ++j) {
            float4 g = ge4[lane + j * 64];
            acc += xr[j].x * g.x + xr[j].y * g.y + xr[j].z * g.z + xr[j].w * g.w;
        }
#pragma unroll
        for (int off = 32; off; off >>= 1) acc += __shfl_xor(acc, off, 64);
        logits[e] = acc;
    }
    if (lane == 0) {
        float m = logits[0];
#pragma unroll
        for (int e = 1; e < E; ++e) m = fmaxf(m, logits[e]);
        float p[E];
#pragma unroll
        for (int e = 0; e < E; ++e) p[e] = __expf(logits[e] - m);
        int sel[TOPK]; float wv[TOPK]; float tot = 0.f;
#pragma unroll
        for (int k = 0; k < TOPK; ++k) {
            int best = 0; float bv = -1.f;
#pragma unroll
            for (int e = 0; e < E; ++e) { if (p[e] > bv) { bv = p[e]; best = e; } }
            sel[k] = best; wv[k] = bv; tot += bv; p[best] = -2.f;
        }
#pragma unroll
        for (int k = 0; k < TOPK; ++k) {
            topk_idx[tok * TOPK + k] = sel[k];
            topk_w[tok * TOPK + k] = wv[k] / tot;
        }
    }
}

// ---------------- route_build: hist + scan + scatter in ONE single block ----------------
// 1024 threads, 8 pairs each. All atomics are LDS-scope (16 addresses, one CU).
// Emits pair_token + pair_w (per-pair routing weight for gemm_b's fused combine).
__global__ __launch_bounds__(1024) void route_build_kernel(
    const int* __restrict__ topk_idx, const float* __restrict__ topk_w,
    int* __restrict__ offsets,
    int* __restrict__ pair_token, float* __restrict__ pair_w)
{
    __shared__ int h[E];
    __shared__ int cur[E];
    int tid = threadIdx.x;
    if (tid < E) h[tid] = 0;
    __syncthreads();
    int eloc[8];
#pragma unroll
    for (int j = 0; j < 8; ++j) {
        eloc[j] = topk_idx[tid * 8 + j];
        atomicAdd(&h[eloc[j]], 1);
    }
    __syncthreads();
    if (tid == 0) {
        int s = 0;
#pragma unroll
        for (int e = 0; e < E; ++e) { offsets[e] = s; cur[e] = s; s += h[e]; }
        offsets[E] = s;
    }
    __syncthreads();
#pragma unroll
    for (int j = 0; j < 8; ++j) {
        int i = tid * 8 + j;
        int pos = atomicAdd(&cur[eloc[j]], 1);
        pair_token[pos] = i >> 2;
        pair_w[pos] = topk_w[i];
    }
}

// Swizzle (BK=32): global (row, chunk c in 0..3) stored at 16B-slot
//   s = (c + 4*(row&1)) ^ ((row>>1)&7) within 2-row granule (row>>1).
// Read (m, cc): addr_elems = (m>>1)*64 + ((cc + 4*(m&1)) ^ ((m>>1)&7))*8.
// Balance proof: per ds_read_b128 each bank-quad gets exactly 8 of 64 lanes.

// ---------------- GEMM A: act = silu(Xg@w1^T)*(Xg@w3^T) ----------------
// 128x64 dual tile, BK=32, dbuf 32KB LDS, XCD swizzle.
// FROZEN (R0/R5-verified ~45us): R1 proved schedule-invariant, R3 proved
// traffic-bound (time ~ staged bytes / ~5.7 TB/s cache-side BW at 2 live/CU),
// R9 proved in-kernel routing recompute costs +19us (keep route_build separate).
__global__ __launch_bounds__(256, 5) void gemm_a_kernel(
    const unsigned short* __restrict__ xb,
    const unsigned short* __restrict__ wb1,
    const unsigned short* __restrict__ wb3,
    const int* __restrict__ offsets,
    const int* __restrict__ pair_token,
    unsigned short* __restrict__ act)
{
    __shared__ unsigned short Xs[2][128 * 32];   // 2 x 8 KB
    __shared__ unsigned short W1s[2][64 * 32];   // 2 x 4 KB
    __shared__ unsigned short W3s[2][64 * 32];   // 2 x 4 KB

    int bid = blockIdx.x;
    int xcd = bid & 7, s0 = bid >> 3;
    int yz = xcd * 16 + (s0 >> 4);
    int e = yz >> 3;
    int n0 = (yz & 7) * 64;
    int t0 = (s0 & 15) * 128;

    int beg = offsets[e];
    int cnt = offsets[e + 1] - beg;
    if (t0 >= cnt) return;

    int tid = threadIdx.x;
    int wave = tid >> 6, lane = tid & 63;

    // staging source pointers (k-invariant): slot -> (row, chunk) via swizzle
    const unsigned short* xg[2];
#pragma unroll
    for (int i = 0; i < 2; ++i) {
        int slot = wave * 128 + i * 64 + lane;
        int g = slot >> 3, sp = (slot & 7) ^ (g & 7);
        int row = g * 2 + (sp >> 2), c = sp & 3;
        int r = t0 + row; if (r >= cnt) r = cnt - 1;
        xg[i] = xb + (size_t)pair_token[beg + r] * H + c * 8;
    }
    const unsigned short* w1g;
    const unsigned short* w3g;
    {
        int slot = wave * 64 + lane;
        int g = slot >> 3, sp = (slot & 7) ^ (g & 7);
        int row = g * 2 + (sp >> 2), c = sp & 3;
        size_t off = (size_t)e * IDIM * H + (size_t)(n0 + row) * H + c * 8;
        w1g = wb1 + off;
        w3g = wb3 + off;
    }

    int wr = wave >> 1, wc = wave & 1;
    int lm = lane & 15, lq = lane >> 4;

    f32x4 acc1[4][2], acc3[4][2];
#pragma unroll
    for (int mi = 0; mi < 4; ++mi)
#pragma unroll
        for (int nj = 0; nj < 2; ++nj) {
            acc1[mi][nj] = (f32x4){0.f, 0.f, 0.f, 0.f};
            acc3[mi][nj] = (f32x4){0.f, 0.f, 0.f, 0.f};
        }

    // precompute frag-read LDS offsets (element units)
    int aoff[4], boff[2];
#pragma unroll
    for (int mi = 0; mi < 4; ++mi) {
        int m = wr * 64 + mi * 16 + lm;
        int g = m >> 1;
        aoff[mi] = g * 64 + (((lq + ((m & 1) << 2)) ^ (g & 7)) << 3);
    }
#pragma unroll
    for (int nj = 0; nj < 2; ++nj) {
        int n = wc * 32 + nj * 16 + lm;
        int g = n >> 1;
        boff[nj] = g * 64 + (((lq + ((n & 1) << 2)) ^ (g & 7)) << 3);
    }

    // prologue
#pragma unroll
    for (int i = 0; i < 2; ++i) async_ld16(xg[i], &Xs[0][(wave * 128 + i * 64) * 8]);
    async_ld16(w1g, &W1s[0][wave * 512]);
    async_ld16(w3g, &W3s[0][wave * 512]);

    const int NK = H / 32;
    for (int kk = 0; kk < NK; ++kk) {
        int cur = kk & 1;
        __syncthreads();
        if (kk + 1 < NK) {
            int nxt = cur ^ 1;
            int k1 = (kk + 1) * 32;
#pragma unroll
            for (int i = 0; i < 2; ++i) async_ld16(xg[i] + k1, &Xs[nxt][(wave * 128 + i * 64) * 8]);
            async_ld16(w1g + k1, &W1s[nxt][wave * 512]);
            async_ld16(w3g + k1, &W3s[nxt][wave * 512]);
        }
        bf16x8 af[4], b1[2], b3[2];
#pragma unroll
        for (int mi = 0; mi < 4; ++mi) af[mi] = *(const bf16x8*)&Xs[cur][aoff[mi]];
#pragma unroll
        for (int nj = 0; nj < 2; ++nj) {
            b1[nj] = *(const bf16x8*)&W1s[cur][boff[nj]];
            b3[nj] = *(const bf16x8*)&W3s[cur][boff[nj]];
        }
#pragma unroll
        for (int mi = 0; mi < 4; ++mi)
#pragma unroll
            for (int nj = 0; nj < 2; ++nj) {
                acc1[mi][nj] = __builtin_amdgcn_mfma_f32_16x16x32_bf16(af[mi], b1[nj], acc1[mi][nj], 0, 0, 0);
                acc3[mi][nj] = __builtin_amdgcn_mfma_f32_16x16x32_bf16(af[mi], b3[nj], acc3[mi][nj], 0, 0, 0);
            }
    }
#pragma unroll
    for (int mi = 0; mi < 4; ++mi) {
#pragma unroll
        for (int r = 0; r < 4; ++r) {
            int trow = t0 + wr * 64 + mi * 16 + lq * 4 + r;
            if (trow < cnt) {
                size_t base = (size_t)(beg + trow) * IDIM + n0 + wc * 32 + lm;
#pragma unroll
                for (int nj = 0; nj < 2; ++nj) {
                    float h1 = acc1[mi][nj][r];
                    float sg = h1 / (1.f + __expf(-h1));
                    act[base + nj * 16] = f2bf(sg * acc3[mi][nj][r]);
                }
            }
        }
    }
}

// ---------------- GEMM B + fused combine: out[token,:] += w * (act @ w2^T) -------------
// 128x64 tile, BK=32, dbuf 24KB LDS, XCD swizzle (GEMM body FROZEN, R0/R5).
// Epilogue: fp32 atomicAdd into out — 8.4M atomics over 2M addresses, <=4
// contenders each (NOT the R4 single-line funnel; numerics verified in R2).
// Deletes combine kernel + outp round-trip (16MB write + 16MB gather + 8MB write).
__global__ __launch_bounds__(256, 5) void gemm_b_kernel(
    const unsigned short* __restrict__ act,
    const unsigned short* __restrict__ wb2,
    const int* __restrict__ offsets,
    const int* __restrict__ pair_token,
    const float* __restrict__ pair_w,
    float* __restrict__ out)
{
    __shared__ unsigned short As[2][128 * 32];
    __shared__ unsigned short W2s[2][64 * 32];

    int bid = blockIdx.x;
    int xcd = bid & 7, s0 = bid >> 3;
    int yz = xcd * 32 + (s0 >> 4);
    int e = yz >> 4;
    int h0 = (yz & 15) * 64;
    int t0 = (s0 & 15) * 128;

    int beg = offsets[e];
    int cnt = offsets[e + 1] - beg;
    if (t0 >= cnt) return;

    int tid = threadIdx.x;
    int wave = tid >> 6, lane = tid & 63;

    const unsigned short* ag[2];
#pragma unroll
    for (int i = 0; i < 2; ++i) {
        int slot = wave * 128 + i * 64 + lane;
        int g = slot >> 3, sp = (slot & 7) ^ (g & 7);
        int row = g * 2 + (sp >> 2), c = sp & 3;
        int ar = beg + t0 + row; if (ar > NPAIR - 1) ar = NPAIR - 1;
        ag[i] = act + (size_t)ar * IDIM + c * 8;
    }
    const unsigned short* w2g;
    {
        int slot = wave * 64 + lane;
        int g = slot >> 3, sp = (slot & 7) ^ (g & 7);
        int row = g * 2 + (sp >> 2), c = sp & 3;
        w2g = wb2 + (size_t)e * H * IDIM + (size_t)(h0 + row) * IDIM + c * 8;
    }

    int wr = wave >> 1, wc = wave & 1;
    int lm = lane & 15, lq = lane >> 4;

    f32x4 acc[4][2];
#pragma unroll
    for (int mi = 0; mi < 4; ++mi)
#pragma unroll
        for (int nj = 0; nj < 2; ++nj) acc[mi][nj] = (f32x4){0.f, 0.f, 0.f, 0.f};

    int aoff[4], boff[2];
#pragma unroll
    for (int mi = 0; mi < 4; ++mi) {
        int m = wr * 64 + mi * 16 + lm;
        int g = m >> 1;
        aoff[mi] = g * 64 + (((lq + ((m & 1) << 2)) ^ (g & 7)) << 3);
    }
#pragma unroll
    for (int nj = 0; nj < 2; ++nj) {
        int n = wc * 32 + nj * 16 + lm;
        int g = n >> 1;
        boff[nj] = g * 64 + (((lq + ((n & 1) << 2)) ^ (g & 7)) << 3);
    }

#pragma unroll
    for (int i = 0; i < 2; ++i) async_ld16(ag[i], &As[0][(wave * 128 + i * 64) * 8]);
    async_ld16(w2g, &W2s[0][wave * 512]);

    const int NK = IDIM / 32;
    for (int kk = 0; kk < NK; ++kk) {
        int cur = kk & 1;
        __syncthreads();
        if (kk + 1 < NK) {
            int nxt = cur ^ 1;
            int k1 = (kk + 1) * 32;
#pragma unroll
            for (int i = 0; i < 2; ++i) async_ld16(ag[i] + k1, &As[nxt][(wave * 128 + i * 64) * 8]);
            async_ld16(w2g + k1, &W2s[nxt][wave * 512]);
        }
        bf16x8 af[4], bfr[2];
#pragma unroll
        for (int mi = 0; mi < 4; ++mi) af[mi] = *(const bf16x8*)&As[cur][aoff[mi]];
#pragma unroll
        for (int nj = 0; nj < 2; ++nj) bfr[nj] = *(const bf16x8*)&W2s[cur][boff[nj]];
#pragma unroll
        for (int mi = 0; mi < 4; ++mi)
#pragma unroll
            for (int nj = 0; nj < 2; ++nj)
                acc[mi][nj] = __builtin_amdgcn_mfma_f32_16x16x32_bf16(af[mi], bfr[nj], acc[mi][nj], 0, 0, 0);
    }
#pragma unroll
    for (int mi = 0; mi < 4; ++mi) {
#pragma unroll
        for (int r = 0; r < 4; ++r) {
            int trow = t0 + wr * 64 + mi * 16 + lq * 4 + r;
            if (trow < cnt) {
                int p = beg + trow;
                int tok = pair_token[p];
                float wgt = pair_w[p];
                float* orow = out + (size_t)tok * H + h0 + wc * 32 + lm;
                atomicAdd(&orow[0],  wgt * acc[mi][0][r]);
                atomicAdd(&orow[16], wgt * acc[mi][1][r]);
            }
        }
    }
}

extern "C" void kernel_launch(void* const* d_in, const int* in_sizes, int n_in,
                              void* d_out, int out_size, void* d_ws, size_t ws_size,
                              hipStream_t stream)
{
    const float* x  = (const float*)d_in[0];
    const float* gw = (const float*)d_in[1];
    const float* w1 = (const float*)d_in[2];
    const float* w3 = (const float*)d_in[3];
    const float* w2 = (const float*)d_in[4];
    float* out = (float*)d_out;

    char* ws = (char*)d_ws;
    int*   offsets    = (int*)(ws + 128);
    int*   topk_idx   = (int*)(ws + 1024);
    float* topk_w     = (float*)(ws + 33792);
    int*   pair_token = (int*)(ws + 66560);
    float* pair_w     = (float*)(ws + 99328);
    unsigned short* xb  = (unsigned short*)(ws + 262144);    // 4 MB
    unsigned short* wb1 = (unsigned short*)(ws + 8388608);   // 16 MB
    unsigned short* wb3 = (unsigned short*)(ws + 25165824);  // 16 MB
    unsigned short* wb2 = (unsigned short*)(ws + 41943040);  // 16 MB
    unsigned short* act = (unsigned short*)(ws + 58720256);  // 8 MB

    router_kernel<<<T / 4, 256, 0, stream>>>(x, gw, topk_idx, topk_w, xb, out);
    route_build_kernel<<<1, 1024, 0, stream>>>(topk_idx, topk_w, offsets, pair_token, pair_w);

    cvt3_kernel<<<3 * 2048, 256, 0, stream>>>(w1, w3, w2, wb1, wb3, wb2);

    gemm_a_kernel<<<2048, 256, 0, stream>>>(xb, wb1, wb3, offsets, pair_token, act);
    gemm_b_kernel<<<4096, 256, 0, stream>>>(act, wb2, offsets, pair_token, pair_w, out);
}

// Round 12
// 223.298 us; speedup vs baseline: 1.0705x; 1.0705x over previous
//
#include <hip/hip_runtime.h>
#include <hip/hip_bf16.h>

#define T 2048
#define H 1024
#define IDIM 512
#define E 16
#define TOPK 4
#define NPAIR (T * TOPK)

typedef short bf16x8 __attribute__((ext_vector_type(8)));
typedef float f32x4 __attribute__((ext_vector_type(4)));
typedef unsigned short u16x8 __attribute__((ext_vector_type(8)));

static __device__ __forceinline__ unsigned short f2bf(float f) {
    union { float f; unsigned int u; } v; v.f = f;
    unsigned int r = (v.u + 0x7FFFu + ((v.u >> 16) & 1u)) >> 16;  // RNE
    return (unsigned short)r;
}
static __device__ __forceinline__ float bf2f(unsigned short s) {
    union { unsigned int u; float f; } v; v.u = ((unsigned int)s) << 16;
    return v.f;
}

static __device__ __forceinline__ void async_ld16(const unsigned short* g, unsigned short* l) {
    __builtin_amdgcn_global_load_lds((const __attribute__((address_space(1))) void*)g,
                                     (__attribute__((address_space(3))) void*)l, 16, 0, 0);
}

// ---------------- fp32 -> bf16 weights: 16B-wide stores ----------------
__global__ __launch_bounds__(256) void cvt3_kernel(
    const float* __restrict__ w1, const float* __restrict__ w3, const float* __restrict__ w2,
    unsigned short* __restrict__ d1, unsigned short* __restrict__ d3, unsigned short* __restrict__ d2)
{
    const int n8 = (E * IDIM * H) / 8;      // per-region float8 count (1M)
    int region = blockIdx.x >> 11;          // 3 regions x 2048 blocks
    int bid = blockIdx.x & 2047;
    const float* src = (region == 0) ? w1 : (region == 1) ? w3 : w2;
    unsigned short* dst = (region == 0) ? d1 : (region == 1) ? d3 : d2;
    int i = bid * 256 + threadIdx.x;
    const int stride = 2048 * 256;
#pragma unroll 2
    for (; i < n8; i += stride) {
        float4 a = ((const float4*)src)[2 * i];
        float4 b = ((const float4*)src)[2 * i + 1];
        u16x8 o;
        o[0] = f2bf(a.x); o[1] = f2bf(a.y); o[2] = f2bf(a.z); o[3] = f2bf(a.w);
        o[4] = f2bf(b.x); o[5] = f2bf(b.y); o[6] = f2bf(b.z); o[7] = f2bf(b.w);
        ((u16x8*)dst)[i] = o;
    }
}

// ---------------- Router (fp32 exact) + fused x->bf16 ----------------
// NO global histogram atomics (R4: 8192 device atomics to one line = ~100us).
__global__ __launch_bounds__(256) void router_kernel(
    const float* __restrict__ x, const float* __restrict__ gw,
    int* __restrict__ topk_idx, float* __restrict__ topk_w,
    unsigned short* __restrict__ xb)
{
    int tok = blockIdx.x * 4 + (threadIdx.x >> 6);
    int lane = threadIdx.x & 63;
    if (tok >= T) return;
    const float4* xt4 = (const float4*)(x + (size_t)tok * H);
    float4 xr[4];
#pragma unroll
    for (int j = 0; j < 4; ++j) xr[j] = xt4[lane + j * 64];
    ushort4* xbt = (ushort4*)(xb + (size_t)tok * H);
#pragma unroll
    for (int j = 0; j < 4; ++j) {
        ushort4 o;
        o.x = f2bf(xr[j].x); o.y = f2bf(xr[j].y);
        o.z = f2bf(xr[j].z); o.w = f2bf(xr[j].w);
        xbt[lane + j * 64] = o;
    }
    float logits[E];
#pragma unroll
    for (int e = 0; e < E; ++e) {
        const float4* ge4 = (const float4*)(gw + (size_t)e * H);
        float acc = 0.f;
#pragma unroll
        for (int j = 0; j < 4; ++j) {
            float4 g = ge4[lane + j * 64];
            acc += xr[j].x * g.x + xr[j].y * g.y + xr[j].z * g.z + xr[j].w * g.w;
        }
#pragma unroll
        for (int off = 32; off; off >>= 1) acc += __shfl_xor(acc, off, 64);
        logits[e] = acc;
    }
    if (lane == 0) {
        float m = logits[0];
#pragma unroll
        for (int e = 1; e < E; ++e) m = fmaxf(m, logits[e]);
        float p[E];
#pragma unroll
        for (int e = 0; e < E; ++e) p[e] = __expf(logits[e] - m);
        int sel[TOPK]; float wv[TOPK]; float tot = 0.f;
#pragma unroll
        for (int k = 0; k < TOPK; ++k) {
            int best = 0; float bv = -1.f;
#pragma unroll
            for (int e = 0; e < E; ++e) { if (p[e] > bv) { bv = p[e]; best = e; } }
            sel[k] = best; wv[k] = bv; tot += bv; p[best] = -2.f;
        }
#pragma unroll
        for (int k = 0; k < TOPK; ++k) {
            topk_idx[tok * TOPK + k] = sel[k];
            topk_w[tok * TOPK + k] = wv[k] / tot;
        }
    }
}

// ---------------- route_build: hist + scan + scatter in ONE single block ----------------
// 1024 threads, 8 pairs each. All atomics are LDS-scope (16 addresses, one CU).
__global__ __launch_bounds__(1024) void route_build_kernel(
    const int* __restrict__ topk_idx, int* __restrict__ offsets,
    int* __restrict__ pair_token, int* __restrict__ inv_pos)
{
    __shared__ int h[E];
    __shared__ int cur[E];
    int tid = threadIdx.x;
    if (tid < E) h[tid] = 0;
    __syncthreads();
    int eloc[8];
#pragma unroll
    for (int j = 0; j < 8; ++j) {
        eloc[j] = topk_idx[tid * 8 + j];
        atomicAdd(&h[eloc[j]], 1);
    }
    __syncthreads();
    if (tid == 0) {
        int s = 0;
#pragma unroll
        for (int e = 0; e < E; ++e) { offsets[e] = s; cur[e] = s; s += h[e]; }
        offsets[E] = s;
    }
    __syncthreads();
#pragma unroll
    for (int j = 0; j < 8; ++j) {
        int i = tid * 8 + j;
        int pos = atomicAdd(&cur[eloc[j]], 1);
        pair_token[pos] = i >> 2;
        inv_pos[i] = pos;
    }
}

// Swizzle (BK=32): global (row, chunk c in 0..3) stored at 16B-slot
//   s = (c + 4*(row&1)) ^ ((row>>1)&7) within 2-row granule (row>>1).
// Read (m, cc): addr_elems = (m>>1)*64 + ((cc + 4*(m&1)) ^ ((m>>1)&7))*8.
// Balance proof: per ds_read_b128 each bank-quad gets exactly 8 of 64 lanes.

// ---------------- GEMM A: act = silu(Xg@w1^T)*(Xg@w3^T) ----------------
// 128x64 dual tile, BK=32, dbuf 32KB LDS, XCD swizzle.
// FROZEN (R0/R5-verified ~45us): R1 proved schedule-invariant, R3/R8 proved
// traffic x concurrency tradeoff is flat-to-negative in every direction,
// R9 proved in-kernel routing recompute costs +19us, R10 proved atomic
// epilogues cost more than they save.
__global__ __launch_bounds__(256, 5) void gemm_a_kernel(
    const unsigned short* __restrict__ xb,
    const unsigned short* __restrict__ wb1,
    const unsigned short* __restrict__ wb3,
    const int* __restrict__ offsets,
    const int* __restrict__ pair_token,
    unsigned short* __restrict__ act)
{
    __shared__ unsigned short Xs[2][128 * 32];   // 2 x 8 KB
    __shared__ unsigned short W1s[2][64 * 32];   // 2 x 4 KB
    __shared__ unsigned short W3s[2][64 * 32];   // 2 x 4 KB

    int bid = blockIdx.x;
    int xcd = bid & 7, s0 = bid >> 3;
    int yz = xcd * 16 + (s0 >> 4);
    int e = yz >> 3;
    int n0 = (yz & 7) * 64;
    int t0 = (s0 & 15) * 128;

    int beg = offsets[e];
    int cnt = offsets[e + 1] - beg;
    if (t0 >= cnt) return;

    int tid = threadIdx.x;
    int wave = tid >> 6, lane = tid & 63;

    // staging source pointers (k-invariant): slot -> (row, chunk) via swizzle
    const unsigned short* xg[2];
#pragma unroll
    for (int i = 0; i < 2; ++i) {
        int slot = wave * 128 + i * 64 + lane;
        int g = slot >> 3, sp = (slot & 7) ^ (g & 7);
        int row = g * 2 + (sp >> 2), c = sp & 3;
        int r = t0 + row; if (r >= cnt) r = cnt - 1;
        xg[i] = xb + (size_t)pair_token[beg + r] * H + c * 8;
    }
    const unsigned short* w1g;
    const unsigned short* w3g;
    {
        int slot = wave * 64 + lane;
        int g = slot >> 3, sp = (slot & 7) ^ (g & 7);
        int row = g * 2 + (sp >> 2), c = sp & 3;
        size_t off = (size_t)e * IDIM * H + (size_t)(n0 + row) * H + c * 8;
        w1g = wb1 + off;
        w3g = wb3 + off;
    }

    int wr = wave >> 1, wc = wave & 1;
    int lm = lane & 15, lq = lane >> 4;

    f32x4 acc1[4][2], acc3[4][2];
#pragma unroll
    for (int mi = 0; mi < 4; ++mi)
#pragma unroll
        for (int nj = 0; nj < 2; ++nj) {
            acc1[mi][nj] = (f32x4){0.f, 0.f, 0.f, 0.f};
            acc3[mi][nj] = (f32x4){0.f, 0.f, 0.f, 0.f};
        }

    // precompute frag-read LDS offsets (element units)
    int aoff[4], boff[2];
#pragma unroll
    for (int mi = 0; mi < 4; ++mi) {
        int m = wr * 64 + mi * 16 + lm;
        int g = m >> 1;
        aoff[mi] = g * 64 + (((lq + ((m & 1) << 2)) ^ (g & 7)) << 3);
    }
#pragma unroll
    for (int nj = 0; nj < 2; ++nj) {
        int n = wc * 32 + nj * 16 + lm;
        int g = n >> 1;
        boff[nj] = g * 64 + (((lq + ((n & 1) << 2)) ^ (g & 7)) << 3);
    }

    // prologue
#pragma unroll
    for (int i = 0; i < 2; ++i) async_ld16(xg[i], &Xs[0][(wave * 128 + i * 64) * 8]);
    async_ld16(w1g, &W1s[0][wave * 512]);
    async_ld16(w3g, &W3s[0][wave * 512]);

    const int NK = H / 32;
    for (int kk = 0; kk < NK; ++kk) {
        int cur = kk & 1;
        __syncthreads();
        if (kk + 1 < NK) {
            int nxt = cur ^ 1;
            int k1 = (kk + 1) * 32;
#pragma unroll
            for (int i = 0; i < 2; ++i) async_ld16(xg[i] + k1, &Xs[nxt][(wave * 128 + i * 64) * 8]);
            async_ld16(w1g + k1, &W1s[nxt][wave * 512]);
            async_ld16(w3g + k1, &W3s[nxt][wave * 512]);
        }
        bf16x8 af[4], b1[2], b3[2];
#pragma unroll
        for (int mi = 0; mi < 4; ++mi) af[mi] = *(const bf16x8*)&Xs[cur][aoff[mi]];
#pragma unroll
        for (int nj = 0; nj < 2; ++nj) {
            b1[nj] = *(const bf16x8*)&W1s[cur][boff[nj]];
            b3[nj] = *(const bf16x8*)&W3s[cur][boff[nj]];
        }
#pragma unroll
        for (int mi = 0; mi < 4; ++mi)
#pragma unroll
            for (int nj = 0; nj < 2; ++nj) {
                acc1[mi][nj] = __builtin_amdgcn_mfma_f32_16x16x32_bf16(af[mi], b1[nj], acc1[mi][nj], 0, 0, 0);
                acc3[mi][nj] = __builtin_amdgcn_mfma_f32_16x16x32_bf16(af[mi], b3[nj], acc3[mi][nj], 0, 0, 0);
            }
    }
#pragma unroll
    for (int mi = 0; mi < 4; ++mi) {
#pragma unroll
        for (int r = 0; r < 4; ++r) {
            int trow = t0 + wr * 64 + mi * 16 + lq * 4 + r;
            if (trow < cnt) {
                size_t base = (size_t)(beg + trow) * IDIM + n0 + wc * 32 + lm;
#pragma unroll
                for (int nj = 0; nj < 2; ++nj) {
                    float h1 = acc1[mi][nj][r];
                    float sg = h1 / (1.f + __expf(-h1));
                    act[base + nj * 16] = f2bf(sg * acc3[mi][nj][r]);
                }
            }
        }
    }
}

// ---------------- GEMM B: outp_bf16[pos,:] = act @ w2^T ----------------
// 128x64 tile, BK=32, dbuf 24KB LDS, XCD swizzle. FROZEN (R0/R5-verified).
__global__ __launch_bounds__(256, 5) void gemm_b_kernel(
    const unsigned short* __restrict__ act,
    const unsigned short* __restrict__ wb2,
    const int* __restrict__ offsets,
    unsigned short* __restrict__ outp)
{
    __shared__ unsigned short As[2][128 * 32];
    __shared__ unsigned short W2s[2][64 * 32];

    int bid = blockIdx.x;
    int xcd = bid & 7, s0 = bid >> 3;
    int yz = xcd * 32 + (s0 >> 4);
    int e = yz >> 4;
    int h0 = (yz & 15) * 64;
    int t0 = (s0 & 15) * 128;

    int beg = offsets[e];
    int cnt = offsets[e + 1] - beg;
    if (t0 >= cnt) return;

    int tid = threadIdx.x;
    int wave = tid >> 6, lane = tid & 63;

    const unsigned short* ag[2];
#pragma unroll
    for (int i = 0; i < 2; ++i) {
        int slot = wave * 128 + i * 64 + lane;
        int g = slot >> 3, sp = (slot & 7) ^ (g & 7);
        int row = g * 2 + (sp >> 2), c = sp & 3;
        int ar = beg + t0 + row; if (ar > NPAIR - 1) ar = NPAIR - 1;
        ag[i] = act + (size_t)ar * IDIM + c * 8;
    }
    const unsigned short* w2g;
    {
        int slot = wave * 64 + lane;
        int g = slot >> 3, sp = (slot & 7) ^ (g & 7);
        int row = g * 2 + (sp >> 2), c = sp & 3;
        w2g = wb2 + (size_t)e * H * IDIM + (size_t)(h0 + row) * IDIM + c * 8;
    }

    int wr = wave >> 1, wc = wave & 1;
    int lm = lane & 15, lq = lane >> 4;

    f32x4 acc[4][2];
#pragma unroll
    for (int mi = 0; mi < 4; ++mi)
#pragma unroll
        for (int nj = 0; nj < 2; ++nj) acc[mi][nj] = (f32x4){0.f, 0.f, 0.f, 0.f};

    int aoff[4], boff[2];
#pragma unroll
    for (int mi = 0; mi < 4; ++mi) {
        int m = wr * 64 + mi * 16 + lm;
        int g = m >> 1;
        aoff[mi] = g * 64 + (((lq + ((m & 1) << 2)) ^ (g & 7)) << 3);
    }
#pragma unroll
    for (int nj = 0; nj < 2; ++nj) {
        int n = wc * 32 + nj * 16 + lm;
        int g = n >> 1;
        boff[nj] = g * 64 + (((lq + ((n & 1) << 2)) ^ (g & 7)) << 3);
    }

#pragma unroll
    for (int i = 0; i < 2; ++i) async_ld16(ag[i], &As[0][(wave * 128 + i * 64) * 8]);
    async_ld16(w2g, &W2s[0][wave * 512]);

    const int NK = IDIM / 32;
    for (int kk = 0; kk < NK; ++kk) {
        int cur = kk & 1;
        __syncthreads();
        if (kk + 1 < NK) {
            int nxt = cur ^ 1;
            int k1 = (kk + 1) * 32;
#pragma unroll
            for (int i = 0; i < 2; ++i) async_ld16(ag[i] + k1, &As[nxt][(wave * 128 + i * 64) * 8]);
            async_ld16(w2g + k1, &W2s[nxt][wave * 512]);
        }
        bf16x8 af[4], bfr[2];
#pragma unroll
        for (int mi = 0; mi < 4; ++mi) af[mi] = *(const bf16x8*)&As[cur][aoff[mi]];
#pragma unroll
        for (int nj = 0; nj < 2; ++nj) bfr[nj] = *(const bf16x8*)&W2s[cur][boff[nj]];
#pragma unroll
        for (int mi = 0; mi < 4; ++mi)
#pragma unroll
            for (int nj = 0; nj < 2; ++nj)
                acc[mi][nj] = __builtin_amdgcn_mfma_f32_16x16x32_bf16(af[mi], bfr[nj], acc[mi][nj], 0, 0, 0);
    }
#pragma unroll
    for (int mi = 0; mi < 4; ++mi) {
#pragma unroll
        for (int r = 0; r < 4; ++r) {
            int trow = t0 + wr * 64 + mi * 16 + lq * 4 + r;
            if (trow < cnt) {
                unsigned short* orow = outp + (size_t)(beg + trow) * H + h0 + wc * 32 + lm;
#pragma unroll
                for (int nj = 0; nj < 2; ++nj) orow[nj * 16] = f2bf(acc[mi][nj][r]);
            }
        }
    }
}

// ---------------- Combine ----------------
__global__ __launch_bounds__(256) void combine_kernel(
    const unsigned short* __restrict__ outp, const int* __restrict__ inv_pos,
    const float* __restrict__ topk_w, float* __restrict__ out)
{
    int gid = blockIdx.x * 256 + threadIdx.x;
    int t = gid >> 8;
    int c4 = gid & 255;
    float4 a = make_float4(0.f, 0.f, 0.f, 0.f);
#pragma unroll
    for (int k = 0; k < TOPK; ++k) {
        int pos = inv_pos[t * TOPK + k];
        float w = topk_w[t * TOPK + k];
        ushort4 v = ((const ushort4*)(outp + (size_t)pos * H))[c4];
        a.x += w * bf2f(v.x); a.y += w * bf2f(v.y);
        a.z += w * bf2f(v.z); a.w += w * bf2f(v.w);
    }
    *(float4*)(out + (size_t)t * H + c4 * 4) = a;
}

extern "C" void kernel_launch(void* const* d_in, const int* in_sizes, int n_in,
                              void* d_out, int out_size, void* d_ws, size_t ws_size,
                              hipStream_t stream)
{
    const float* x  = (const float*)d_in[0];
    const float* gw = (const float*)d_in[1];
    const float* w1 = (const float*)d_in[2];
    const float* w3 = (const float*)d_in[3];
    const float* w2 = (const float*)d_in[4];
    float* out = (float*)d_out;

    char* ws = (char*)d_ws;
    int*   offsets    = (int*)(ws + 128);
    int*   topk_idx   = (int*)(ws + 1024);
    float* topk_w     = (float*)(ws + 33792);
    int*   pair_token = (int*)(ws + 66560);
    int*   inv_pos    = (int*)(ws + 99328);
    unsigned short* xb  = (unsigned short*)(ws + 262144);    // 4 MB
    unsigned short* wb1 = (unsigned short*)(ws + 8388608);   // 16 MB
    unsigned short* wb3 = (unsigned short*)(ws + 25165824);  // 16 MB
    unsigned short* wb2 = (unsigned short*)(ws + 41943040);  // 16 MB
    unsigned short* act = (unsigned short*)(ws + 58720256);  // 8 MB
    unsigned short* outp = (unsigned short*)(ws + 8388608);  // 16 MB, aliases wb1 (dead after gemm_a)

    hipMemsetAsync(ws, 0, 256, stream);

    router_kernel<<<T / 4, 256, 0, stream>>>(x, gw, topk_idx, topk_w, xb);
    route_build_kernel<<<1, 1024, 0, stream>>>(topk_idx, offsets, pair_token, inv_pos);

    cvt3_kernel<<<3 * 2048, 256, 0, stream>>>(w1, w3, w2, wb1, wb3, wb2);

    gemm_a_kernel<<<2048, 256, 0, stream>>>(xb, wb1, wb3, offsets, pair_token, act);
    gemm_b_kernel<<<4096, 256, 0, stream>>>(act, wb2, offsets, outp);
    combine_kernel<<<(T * H / 4) / 256, 256, 0, stream>>>(outp, inv_pos, topk_w, out);
}

// Round 13
// 215.679 us; speedup vs baseline: 1.1084x; 1.0353x over previous
//
#include <hip/hip_runtime.h>
#include <hip/hip_bf16.h>

#define T 2048
#define H 1024
#define IDIM 512
#define E 16
#define TOPK 4
#define NPAIR (T * TOPK)

typedef short bf16x8 __attribute__((ext_vector_type(8)));
typedef float f32x4 __attribute__((ext_vector_type(4)));
typedef unsigned short u16x8 __attribute__((ext_vector_type(8)));

static __device__ __forceinline__ unsigned short f2bf(float f) {
    union { float f; unsigned int u; } v; v.f = f;
    unsigned int r = (v.u + 0x7FFFu + ((v.u >> 16) & 1u)) >> 16;  // RNE
    return (unsigned short)r;
}
static __device__ __forceinline__ float bf2f(unsigned short s) {
    union { unsigned int u; float f; } v; v.u = ((unsigned int)s) << 16;
    return v.f;
}

static __device__ __forceinline__ void async_ld16(const unsigned short* g, unsigned short* l) {
    __builtin_amdgcn_global_load_lds((const __attribute__((address_space(1))) void*)g,
                                     (__attribute__((address_space(3))) void*)l, 16, 0, 0);
}

// ---------------- Router (fp32 exact) + fused x->bf16 ----------------
// NO global histogram atomics (R4: 8192 device atomics to one line = ~100us).
__global__ __launch_bounds__(256) void router_kernel(
    const float* __restrict__ x, const float* __restrict__ gw,
    int* __restrict__ topk_idx, float* __restrict__ topk_w,
    unsigned short* __restrict__ xb)
{
    int tok = blockIdx.x * 4 + (threadIdx.x >> 6);
    int lane = threadIdx.x & 63;
    if (tok >= T) return;
    const float4* xt4 = (const float4*)(x + (size_t)tok * H);
    float4 xr[4];
#pragma unroll
    for (int j = 0; j < 4; ++j) xr[j] = xt4[lane + j * 64];
    ushort4* xbt = (ushort4*)(xb + (size_t)tok * H);
#pragma unroll
    for (int j = 0; j < 4; ++j) {
        ushort4 o;
        o.x = f2bf(xr[j].x); o.y = f2bf(xr[j].y);
        o.z = f2bf(xr[j].z); o.w = f2bf(xr[j].w);
        xbt[lane + j * 64] = o;
    }
    float logits[E];
#pragma unroll
    for (int e = 0; e < E; ++e) {
        const float4* ge4 = (const float4*)(gw + (size_t)e * H);
        float acc = 0.f;
#pragma unroll
        for (int j = 0; j < 4; ++j) {
            float4 g = ge4[lane + j * 64];
            acc += xr[j].x * g.x + xr[j].y * g.y + xr[j].z * g.z + xr[j].w * g.w;
        }
#pragma unroll
        for (int off = 32; off; off >>= 1) acc += __shfl_xor(acc, off, 64);
        logits[e] = acc;
    }
    if (lane == 0) {
        float m = logits[0];
#pragma unroll
        for (int e = 1; e < E; ++e) m = fmaxf(m, logits[e]);
        float p[E];
#pragma unroll
        for (int e = 0; e < E; ++e) p[e] = __expf(logits[e] - m);
        int sel[TOPK]; float wv[TOPK]; float tot = 0.f;
#pragma unroll
        for (int k = 0; k < TOPK; ++k) {
            int best = 0; float bv = -1.f;
#pragma unroll
            for (int e = 0; e < E; ++e) { if (p[e] > bv) { bv = p[e]; best = e; } }
            sel[k] = best; wv[k] = bv; tot += bv; p[best] = -2.f;
        }
#pragma unroll
        for (int k = 0; k < TOPK; ++k) {
            topk_idx[tok * TOPK + k] = sel[k];
            topk_w[tok * TOPK + k] = wv[k] / tot;
        }
    }
}

// ---------------- cvt3 + route_build merged: block 0 = routing, blocks 1.. = cvt ------
// route_build is ONE 256-thread block (LDS atomics only, ~2us) riding in a
// 6145-block streaming kernel — unlike R2/R6's failed merges (512 heavy blocks
// + fences), a single light block cannot perturb the BW-bound cvt schedule.
// Stream order (router -> this) provides the dependency for free. -2 nodes.
__global__ __launch_bounds__(256) void cvtrb_kernel(
    const float* __restrict__ w1, const float* __restrict__ w3, const float* __restrict__ w2,
    unsigned short* __restrict__ d1, unsigned short* __restrict__ d3, unsigned short* __restrict__ d2,
    const int* __restrict__ topk_idx, int* __restrict__ offsets,
    int* __restrict__ pair_token, int* __restrict__ inv_pos)
{
    int tid = threadIdx.x;
    if (blockIdx.x == 0) {
        // ---- route_build: hist + scan + scatter, 32 pairs/thread ----
        __shared__ int h[E];
        __shared__ int cur[E];
        if (tid < E) h[tid] = 0;
        __syncthreads();
        int eloc[32];
#pragma unroll
        for (int j = 0; j < 32; ++j) {
            eloc[j] = topk_idx[tid * 32 + j];
            atomicAdd(&h[eloc[j]], 1);
        }
        __syncthreads();
        if (tid == 0) {
            int s = 0;
#pragma unroll
            for (int e = 0; e < E; ++e) { offsets[e] = s; cur[e] = s; s += h[e]; }
            offsets[E] = s;
        }
        __syncthreads();
#pragma unroll
        for (int j = 0; j < 32; ++j) {
            int i = tid * 32 + j;
            int pos = atomicAdd(&cur[eloc[j]], 1);
            pair_token[pos] = i >> 2;
            inv_pos[i] = pos;
        }
        return;
    }
    // ---- weight fp32 -> bf16, 16B-wide stores ----
    const int n8 = (E * IDIM * H) / 8;      // per-region float8 count (1M)
    int cb = blockIdx.x - 1;                // 0..6143
    int region = cb >> 11;                  // 3 regions x 2048 blocks
    int bid = cb & 2047;
    const float* src = (region == 0) ? w1 : (region == 1) ? w3 : w2;
    unsigned short* dst = (region == 0) ? d1 : (region == 1) ? d3 : d2;
    int i = bid * 256 + tid;
    const int stride = 2048 * 256;
#pragma unroll 2
    for (; i < n8; i += stride) {
        float4 a = ((const float4*)src)[2 * i];
        float4 b = ((const float4*)src)[2 * i + 1];
        u16x8 o;
        o[0] = f2bf(a.x); o[1] = f2bf(a.y); o[2] = f2bf(a.z); o[3] = f2bf(a.w);
        o[4] = f2bf(b.x); o[5] = f2bf(b.y); o[6] = f2bf(b.z); o[7] = f2bf(b.w);
        ((u16x8*)dst)[i] = o;
    }
}

// Swizzle (BK=32): global (row, chunk c in 0..3) stored at 16B-slot
//   s = (c + 4*(row&1)) ^ ((row>>1)&7) within 2-row granule (row>>1).
// Read (m, cc): addr_elems = (m>>1)*64 + ((cc + 4*(m&1)) ^ ((m>>1)&7))*8.
// Balance proof: per ds_read_b128 each bank-quad gets exactly 8 of 64 lanes.

// ---------------- GEMM A: act = silu(Xg@w1^T)*(Xg@w3^T) ----------------
// 128x64 dual tile, BK=32, dbuf 32KB LDS, XCD swizzle.
// FROZEN (R0/R5/R12-verified ~45us): R1 proved schedule-invariant, R3/R8
// proved traffic x concurrency tradeoff is flat-to-negative in every
// direction, R9 proved in-kernel routing recompute costs +19us, R10 proved
// atomic epilogues cost more than they save.
__global__ __launch_bounds__(256, 5) void gemm_a_kernel(
    const unsigned short* __restrict__ xb,
    const unsigned short* __restrict__ wb1,
    const unsigned short* __restrict__ wb3,
    const int* __restrict__ offsets,
    const int* __restrict__ pair_token,
    unsigned short* __restrict__ act)
{
    __shared__ unsigned short Xs[2][128 * 32];   // 2 x 8 KB
    __shared__ unsigned short W1s[2][64 * 32];   // 2 x 4 KB
    __shared__ unsigned short W3s[2][64 * 32];   // 2 x 4 KB

    int bid = blockIdx.x;
    int xcd = bid & 7, s0 = bid >> 3;
    int yz = xcd * 16 + (s0 >> 4);
    int e = yz >> 3;
    int n0 = (yz & 7) * 64;
    int t0 = (s0 & 15) * 128;

    int beg = offsets[e];
    int cnt = offsets[e + 1] - beg;
    if (t0 >= cnt) return;

    int tid = threadIdx.x;
    int wave = tid >> 6, lane = tid & 63;

    // staging source pointers (k-invariant): slot -> (row, chunk) via swizzle
    const unsigned short* xg[2];
#pragma unroll
    for (int i = 0; i < 2; ++i) {
        int slot = wave * 128 + i * 64 + lane;
        int g = slot >> 3, sp = (slot & 7) ^ (g & 7);
        int row = g * 2 + (sp >> 2), c = sp & 3;
        int r = t0 + row; if (r >= cnt) r = cnt - 1;
        xg[i] = xb + (size_t)pair_token[beg + r] * H + c * 8;
    }
    const unsigned short* w1g;
    const unsigned short* w3g;
    {
        int slot = wave * 64 + lane;
        int g = slot >> 3, sp = (slot & 7) ^ (g & 7);
        int row = g * 2 + (sp >> 2), c = sp & 3;
        size_t off = (size_t)e * IDIM * H + (size_t)(n0 + row) * H + c * 8;
        w1g = wb1 + off;
        w3g = wb3 + off;
    }

    int wr = wave >> 1, wc = wave & 1;
    int lm = lane & 15, lq = lane >> 4;

    f32x4 acc1[4][2], acc3[4][2];
#pragma unroll
    for (int mi = 0; mi < 4; ++mi)
#pragma unroll
        for (int nj = 0; nj < 2; ++nj) {
            acc1[mi][nj] = (f32x4){0.f, 0.f, 0.f, 0.f};
            acc3[mi][nj] = (f32x4){0.f, 0.f, 0.f, 0.f};
        }

    // precompute frag-read LDS offsets (element units)
    int aoff[4], boff[2];
#pragma unroll
    for (int mi = 0; mi < 4; ++mi) {
        int m = wr * 64 + mi * 16 + lm;
        int g = m >> 1;
        aoff[mi] = g * 64 + (((lq + ((m & 1) << 2)) ^ (g & 7)) << 3);
    }
#pragma unroll
    for (int nj = 0; nj < 2; ++nj) {
        int n = wc * 32 + nj * 16 + lm;
        int g = n >> 1;
        boff[nj] = g * 64 + (((lq + ((n & 1) << 2)) ^ (g & 7)) << 3);
    }

    // prologue
#pragma unroll
    for (int i = 0; i < 2; ++i) async_ld16(xg[i], &Xs[0][(wave * 128 + i * 64) * 8]);
    async_ld16(w1g, &W1s[0][wave * 512]);
    async_ld16(w3g, &W3s[0][wave * 512]);

    const int NK = H / 32;
    for (int kk = 0; kk < NK; ++kk) {
        int cur = kk & 1;
        __syncthreads();
        if (kk + 1 < NK) {
            int nxt = cur ^ 1;
            int k1 = (kk + 1) * 32;
#pragma unroll
            for (int i = 0; i < 2; ++i) async_ld16(xg[i] + k1, &Xs[nxt][(wave * 128 + i * 64) * 8]);
            async_ld16(w1g + k1, &W1s[nxt][wave * 512]);
            async_ld16(w3g + k1, &W3s[nxt][wave * 512]);
        }
        bf16x8 af[4], b1[2], b3[2];
#pragma unroll
        for (int mi = 0; mi < 4; ++mi) af[mi] = *(const bf16x8*)&Xs[cur][aoff[mi]];
#pragma unroll
        for (int nj = 0; nj < 2; ++nj) {
            b1[nj] = *(const bf16x8*)&W1s[cur][boff[nj]];
            b3[nj] = *(const bf16x8*)&W3s[cur][boff[nj]];
        }
#pragma unroll
        for (int mi = 0; mi < 4; ++mi)
#pragma unroll
            for (int nj = 0; nj < 2; ++nj) {
                acc1[mi][nj] = __builtin_amdgcn_mfma_f32_16x16x32_bf16(af[mi], b1[nj], acc1[mi][nj], 0, 0, 0);
                acc3[mi][nj] = __builtin_amdgcn_mfma_f32_16x16x32_bf16(af[mi], b3[nj], acc3[mi][nj], 0, 0, 0);
            }
    }
#pragma unroll
    for (int mi = 0; mi < 4; ++mi) {
#pragma unroll
        for (int r = 0; r < 4; ++r) {
            int trow = t0 + wr * 64 + mi * 16 + lq * 4 + r;
            if (trow < cnt) {
                size_t base = (size_t)(beg + trow) * IDIM + n0 + wc * 32 + lm;
#pragma unroll
                for (int nj = 0; nj < 2; ++nj) {
                    float h1 = acc1[mi][nj][r];
                    float sg = h1 / (1.f + __expf(-h1));
                    act[base + nj * 16] = f2bf(sg * acc3[mi][nj][r]);
                }
            }
        }
    }
}

// ---------------- GEMM B: outp_bf16[pos,:] = act @ w2^T ----------------
// 128x64 tile, BK=32, dbuf 24KB LDS, XCD swizzle. FROZEN (R0/R5-verified).
__global__ __launch_bounds__(256, 5) void gemm_b_kernel(
    const unsigned short* __restrict__ act,
    const unsigned short* __restrict__ wb2,
    const int* __restrict__ offsets,
    unsigned short* __restrict__ outp)
{
    __shared__ unsigned short As[2][128 * 32];
    __shared__ unsigned short W2s[2][64 * 32];

    int bid = blockIdx.x;
    int xcd = bid & 7, s0 = bid >> 3;
    int yz = xcd * 32 + (s0 >> 4);
    int e = yz >> 4;
    int h0 = (yz & 15) * 64;
    int t0 = (s0 & 15) * 128;

    int beg = offsets[e];
    int cnt = offsets[e + 1] - beg;
    if (t0 >= cnt) return;

    int tid = threadIdx.x;
    int wave = tid >> 6, lane = tid & 63;

    const unsigned short* ag[2];
#pragma unroll
    for (int i = 0; i < 2; ++i) {
        int slot = wave * 128 + i * 64 + lane;
        int g = slot >> 3, sp = (slot & 7) ^ (g & 7);
        int row = g * 2 + (sp >> 2), c = sp & 3;
        int ar = beg + t0 + row; if (ar > NPAIR - 1) ar = NPAIR - 1;
        ag[i] = act + (size_t)ar * IDIM + c * 8;
    }
    const unsigned short* w2g;
    {
        int slot = wave * 64 + lane;
        int g = slot >> 3, sp = (slot & 7) ^ (g & 7);
        int row = g * 2 + (sp >> 2), c = sp & 3;
        w2g = wb2 + (size_t)e * H * IDIM + (size_t)(h0 + row) * IDIM + c * 8;
    }

    int wr = wave >> 1, wc = wave & 1;
    int lm = lane & 15, lq = lane >> 4;

    f32x4 acc[4][2];
#pragma unroll
    for (int mi = 0; mi < 4; ++mi)
#pragma unroll
        for (int nj = 0; nj < 2; ++nj) acc[mi][nj] = (f32x4){0.f, 0.f, 0.f, 0.f};

    int aoff[4], boff[2];
#pragma unroll
    for (int mi = 0; mi < 4; ++mi) {
        int m = wr * 64 + mi * 16 + lm;
        int g = m >> 1;
        aoff[mi] = g * 64 + (((lq + ((m & 1) << 2)) ^ (g & 7)) << 3);
    }
#pragma unroll
    for (int nj = 0; nj < 2; ++nj) {
        int n = wc * 32 + nj * 16 + lm;
        int g = n >> 1;
        boff[nj] = g * 64 + (((lq + ((n & 1) << 2)) ^ (g & 7)) << 3);
    }

#pragma unroll
    for (int i = 0; i < 2; ++i) async_ld16(ag[i], &As[0][(wave * 128 + i * 64) * 8]);
    async_ld16(w2g, &W2s[0][wave * 512]);

    const int NK = IDIM / 32;
    for (int kk = 0; kk < NK; ++kk) {
        int cur = kk & 1;
        __syncthreads();
        if (kk + 1 < NK) {
            int nxt = cur ^ 1;
            int k1 = (kk + 1) * 32;
#pragma unroll
            for (int i = 0; i < 2; ++i) async_ld16(ag[i] + k1, &As[nxt][(wave * 128 + i * 64) * 8]);
            async_ld16(w2g + k1, &W2s[nxt][wave * 512]);
        }
        bf16x8 af[4], bfr[2];
#pragma unroll
        for (int mi = 0; mi < 4; ++mi) af[mi] = *(const bf16x8*)&As[cur][aoff[mi]];
#pragma unroll
        for (int nj = 0; nj < 2; ++nj) bfr[nj] = *(const bf16x8*)&W2s[cur][boff[nj]];
#pragma unroll
        for (int mi = 0; mi < 4; ++mi)
#pragma unroll
            for (int nj = 0; nj < 2; ++nj)
                acc[mi][nj] = __builtin_amdgcn_mfma_f32_16x16x32_bf16(af[mi], bfr[nj], acc[mi][nj], 0, 0, 0);
    }
#pragma unroll
    for (int mi = 0; mi < 4; ++mi) {
#pragma unroll
        for (int r = 0; r < 4; ++r) {
            int trow = t0 + wr * 64 + mi * 16 + lq * 4 + r;
            if (trow < cnt) {
                unsigned short* orow = outp + (size_t)(beg + trow) * H + h0 + wc * 32 + lm;
#pragma unroll
                for (int nj = 0; nj < 2; ++nj) orow[nj * 16] = f2bf(acc[mi][nj][r]);
            }
        }
    }
}

// ---------------- Combine ----------------
__global__ __launch_bounds__(256) void combine_kernel(
    const unsigned short* __restrict__ outp, const int* __restrict__ inv_pos,
    const float* __restrict__ topk_w, float* __restrict__ out)
{
    int gid = blockIdx.x * 256 + threadIdx.x;
    int t = gid >> 8;
    int c4 = gid & 255;
    float4 a = make_float4(0.f, 0.f, 0.f, 0.f);
#pragma unroll
    for (int k = 0; k < TOPK; ++k) {
        int pos = inv_pos[t * TOPK + k];
        float w = topk_w[t * TOPK + k];
        ushort4 v = ((const ushort4*)(outp + (size_t)pos * H))[c4];
        a.x += w * bf2f(v.x); a.y += w * bf2f(v.y);
        a.z += w * bf2f(v.z); a.w += w * bf2f(v.w);
    }
    *(float4*)(out + (size_t)t * H + c4 * 4) = a;
}

extern "C" void kernel_launch(void* const* d_in, const int* in_sizes, int n_in,
                              void* d_out, int out_size, void* d_ws, size_t ws_size,
                              hipStream_t stream)
{
    const float* x  = (const float*)d_in[0];
    const float* gw = (const float*)d_in[1];
    const float* w1 = (const float*)d_in[2];
    const float* w3 = (const float*)d_in[3];
    const float* w2 = (const float*)d_in[4];
    float* out = (float*)d_out;

    char* ws = (char*)d_ws;
    int*   offsets    = (int*)(ws + 128);
    int*   topk_idx   = (int*)(ws + 1024);
    float* topk_w     = (float*)(ws + 33792);
    int*   pair_token = (int*)(ws + 66560);
    int*   inv_pos    = (int*)(ws + 99328);
    unsigned short* xb  = (unsigned short*)(ws + 262144);    // 4 MB
    unsigned short* wb1 = (unsigned short*)(ws + 8388608);   // 16 MB
    unsigned short* wb3 = (unsigned short*)(ws + 25165824);  // 16 MB
    unsigned short* wb2 = (unsigned short*)(ws + 41943040);  // 16 MB
    unsigned short* act = (unsigned short*)(ws + 58720256);  // 8 MB
    unsigned short* outp = (unsigned short*)(ws + 8388608);  // 16 MB, aliases wb1 (dead after gemm_a)

    // NOTE: no memset node — route_build fully writes offsets/pair_token/inv_pos;
    // nothing in ws is read before written (audited R13).

    router_kernel<<<T / 4, 256, 0, stream>>>(x, gw, topk_idx, topk_w, xb);

    // block 0 = route_build (needs router: stream-serial), blocks 1..6144 = cvt3
    cvtrb_kernel<<<1 + 3 * 2048, 256, 0, stream>>>(
        w1, w3, w2, wb1, wb3, wb2, topk_idx, offsets, pair_token, inv_pos);

    gemm_a_kernel<<<2048, 256, 0, stream>>>(xb, wb1, wb3, offsets, pair_token, act);
    gemm_b_kernel<<<4096, 256, 0, stream>>>(act, wb2, offsets, outp);
    combine_kernel<<<(T * H / 4) / 256, 256, 0, stream>>>(outp, inv_pos, topk_w, out);
}

// Round 14
// 211.420 us; speedup vs baseline: 1.1307x; 1.0201x over previous
//
#include <hip/hip_runtime.h>
#include <hip/hip_bf16.h>

#define T 2048
#define H 1024
#define IDIM 512
#define E 16
#define TOPK 4
#define NPAIR (T * TOPK)

typedef short bf16x8 __attribute__((ext_vector_type(8)));
typedef float f32x4 __attribute__((ext_vector_type(4)));
typedef unsigned short u16x8 __attribute__((ext_vector_type(8)));

static __device__ __forceinline__ unsigned short f2bf(float f) {
    union { float f; unsigned int u; } v; v.f = f;
    unsigned int r = (v.u + 0x7FFFu + ((v.u >> 16) & 1u)) >> 16;  // RNE
    return (unsigned short)r;
}
static __device__ __forceinline__ float bf2f(unsigned short s) {
    union { unsigned int u; float f; } v; v.u = ((unsigned int)s) << 16;
    return v.f;
}

static __device__ __forceinline__ void async_ld16(const unsigned short* g, unsigned short* l) {
    __builtin_amdgcn_global_load_lds((const __attribute__((address_space(1))) void*)g,
                                     (__attribute__((address_space(3))) void*)l, 16, 0, 0);
}

// ---------------- Router (fp32 exact) + fused x->bf16 ----------------
// NO global histogram atomics (R4: 8192 device atomics to one line = ~100us).
__global__ __launch_bounds__(256) void router_kernel(
    const float* __restrict__ x, const float* __restrict__ gw,
    int* __restrict__ topk_idx, float* __restrict__ topk_w,
    unsigned short* __restrict__ xb)
{
    int tok = blockIdx.x * 4 + (threadIdx.x >> 6);
    int lane = threadIdx.x & 63;
    if (tok >= T) return;
    const float4* xt4 = (const float4*)(x + (size_t)tok * H);
    float4 xr[4];
#pragma unroll
    for (int j = 0; j < 4; ++j) xr[j] = xt4[lane + j * 64];
    ushort4* xbt = (ushort4*)(xb + (size_t)tok * H);
#pragma unroll
    for (int j = 0; j < 4; ++j) {
        ushort4 o;
        o.x = f2bf(xr[j].x); o.y = f2bf(xr[j].y);
        o.z = f2bf(xr[j].z); o.w = f2bf(xr[j].w);
        xbt[lane + j * 64] = o;
    }
    float logits[E];
#pragma unroll
    for (int e = 0; e < E; ++e) {
        const float4* ge4 = (const float4*)(gw + (size_t)e * H);
        float acc = 0.f;
#pragma unroll
        for (int j = 0; j < 4; ++j) {
            float4 g = ge4[lane + j * 64];
            acc += xr[j].x * g.x + xr[j].y * g.y + xr[j].z * g.z + xr[j].w * g.w;
        }
#pragma unroll
        for (int off = 32; off; off >>= 1) acc += __shfl_xor(acc, off, 64);
        logits[e] = acc;
    }
    if (lane == 0) {
        float m = logits[0];
#pragma unroll
        for (int e = 1; e < E; ++e) m = fmaxf(m, logits[e]);
        float p[E];
#pragma unroll
        for (int e = 0; e < E; ++e) p[e] = __expf(logits[e] - m);
        int sel[TOPK]; float wv[TOPK]; float tot = 0.f;
#pragma unroll
        for (int k = 0; k < TOPK; ++k) {
            int best = 0; float bv = -1.f;
#pragma unroll
            for (int e = 0; e < E; ++e) { if (p[e] > bv) { bv = p[e]; best = e; } }
            sel[k] = best; wv[k] = bv; tot += bv; p[best] = -2.f;
        }
#pragma unroll
        for (int k = 0; k < TOPK; ++k) {
            topk_idx[tok * TOPK + k] = sel[k];
            topk_w[tok * TOPK + k] = wv[k] / tot;
        }
    }
}

// ---------------- cvt(w1,w3) + route_build merged (R13-verified ride-along) ----------
// block 0 = route_build (1 light LDS-only block riding in a streaming kernel);
// blocks 1..4096 convert w1,w3. w2's conversion rides inside gemm_a's launch
// (gemm_a doesn't read wb2; only gemm_b does) using gemm_a's idle HBM BW.
__global__ __launch_bounds__(256) void cvtrb_kernel(
    const float* __restrict__ w1, const float* __restrict__ w3,
    unsigned short* __restrict__ d1, unsigned short* __restrict__ d3,
    const int* __restrict__ topk_idx, int* __restrict__ offsets,
    int* __restrict__ pair_token, int* __restrict__ inv_pos)
{
    int tid = threadIdx.x;
    if (blockIdx.x == 0) {
        // ---- route_build: hist + scan + scatter, 32 pairs/thread ----
        __shared__ int h[E];
        __shared__ int cur[E];
        if (tid < E) h[tid] = 0;
        __syncthreads();
        int eloc[32];
#pragma unroll
        for (int j = 0; j < 32; ++j) {
            eloc[j] = topk_idx[tid * 32 + j];
            atomicAdd(&h[eloc[j]], 1);
        }
        __syncthreads();
        if (tid == 0) {
            int s = 0;
#pragma unroll
            for (int e = 0; e < E; ++e) { offsets[e] = s; cur[e] = s; s += h[e]; }
            offsets[E] = s;
        }
        __syncthreads();
#pragma unroll
        for (int j = 0; j < 32; ++j) {
            int i = tid * 32 + j;
            int pos = atomicAdd(&cur[eloc[j]], 1);
            pair_token[pos] = i >> 2;
            inv_pos[i] = pos;
        }
        return;
    }
    // ---- w1/w3 fp32 -> bf16, 16B-wide stores ----
    const int n8 = (E * IDIM * H) / 8;      // per-region float8 count (1M)
    int cb = blockIdx.x - 1;                // 0..4095
    int region = cb >> 11;                  // 2 regions x 2048 blocks
    int bid = cb & 2047;
    const float* src = (region == 0) ? w1 : w3;
    unsigned short* dst = (region == 0) ? d1 : d3;
    int i = bid * 256 + tid;
    const int stride = 2048 * 256;
#pragma unroll 2
    for (; i < n8; i += stride) {
        float4 a = ((const float4*)src)[2 * i];
        float4 b = ((const float4*)src)[2 * i + 1];
        u16x8 o;
        o[0] = f2bf(a.x); o[1] = f2bf(a.y); o[2] = f2bf(a.z); o[3] = f2bf(a.w);
        o[4] = f2bf(b.x); o[5] = f2bf(b.y); o[6] = f2bf(b.z); o[7] = f2bf(b.w);
        ((u16x8*)dst)[i] = o;
    }
}

// Swizzle (BK=32): global (row, chunk c in 0..3) stored at 16B-slot
//   s = (c + 4*(row&1)) ^ ((row>>1)&7) within 2-row granule (row>>1).
// Read (m, cc): addr_elems = (m>>1)*64 + ((cc + 4*(m&1)) ^ ((m>>1)&7))*8.
// Balance proof: per ds_read_b128 each bank-quad gets exactly 8 of 64 lanes.

// ---------------- GEMM A (blocks 0..2047, FROZEN body) + w2-cvt ride-along ----------
// GEMM: 128x64 dual tile, BK=32, dbuf 32KB LDS, XCD swizzle (R0/R5/R12 ~45us;
// R1 schedule-invariant, R3/R8 traffic/concurrency flat, R9/R10 anti-patterns).
// Blocks 2048..4095 convert w2 fp32->bf16: 48MB of streaming riding in gemm_a's
// idle HBM BW (gemm_a uses ~850 GB/s of 8 TB/s). wb2 is consumed by gemm_b
// (next node) — dependency preserved by stream order. Zero atomics/fences.
__global__ __launch_bounds__(256, 5) void gemm_a_kernel(
    const unsigned short* __restrict__ xb,
    const unsigned short* __restrict__ wb1,
    const unsigned short* __restrict__ wb3,
    const float* __restrict__ w2, unsigned short* __restrict__ wb2,
    const int* __restrict__ offsets,
    const int* __restrict__ pair_token,
    unsigned short* __restrict__ act)
{
    int tid = threadIdx.x;
    if (blockIdx.x >= 2048) {
        // ---- w2 fp32 -> bf16 ride-along ----
        const int n8 = (E * H * IDIM) / 8;   // 1M float8
        int cb = blockIdx.x - 2048;          // 0..2047
        int i = cb * 256 + tid;
        const int stride = 2048 * 256;
#pragma unroll 2
        for (; i < n8; i += stride) {
            float4 a = ((const float4*)w2)[2 * i];
            float4 b = ((const float4*)w2)[2 * i + 1];
            u16x8 o;
            o[0] = f2bf(a.x); o[1] = f2bf(a.y); o[2] = f2bf(a.z); o[3] = f2bf(a.w);
            o[4] = f2bf(b.x); o[5] = f2bf(b.y); o[6] = f2bf(b.z); o[7] = f2bf(b.w);
            ((u16x8*)wb2)[i] = o;
        }
        return;
    }

    __shared__ unsigned short Xs[2][128 * 32];   // 2 x 8 KB
    __shared__ unsigned short W1s[2][64 * 32];   // 2 x 4 KB
    __shared__ unsigned short W3s[2][64 * 32];   // 2 x 4 KB

    int bid = blockIdx.x;
    int xcd = bid & 7, s0 = bid >> 3;
    int yz = xcd * 16 + (s0 >> 4);
    int e = yz >> 3;
    int n0 = (yz & 7) * 64;
    int t0 = (s0 & 15) * 128;

    int beg = offsets[e];
    int cnt = offsets[e + 1] - beg;
    if (t0 >= cnt) return;

    int wave = tid >> 6, lane = tid & 63;

    // staging source pointers (k-invariant): slot -> (row, chunk) via swizzle
    const unsigned short* xg[2];
#pragma unroll
    for (int i = 0; i < 2; ++i) {
        int slot = wave * 128 + i * 64 + lane;
        int g = slot >> 3, sp = (slot & 7) ^ (g & 7);
        int row = g * 2 + (sp >> 2), c = sp & 3;
        int r = t0 + row; if (r >= cnt) r = cnt - 1;
        xg[i] = xb + (size_t)pair_token[beg + r] * H + c * 8;
    }
    const unsigned short* w1g;
    const unsigned short* w3g;
    {
        int slot = wave * 64 + lane;
        int g = slot >> 3, sp = (slot & 7) ^ (g & 7);
        int row = g * 2 + (sp >> 2), c = sp & 3;
        size_t off = (size_t)e * IDIM * H + (size_t)(n0 + row) * H + c * 8;
        w1g = wb1 + off;
        w3g = wb3 + off;
    }

    int wr = wave >> 1, wc = wave & 1;
    int lm = lane & 15, lq = lane >> 4;

    f32x4 acc1[4][2], acc3[4][2];
#pragma unroll
    for (int mi = 0; mi < 4; ++mi)
#pragma unroll
        for (int nj = 0; nj < 2; ++nj) {
            acc1[mi][nj] = (f32x4){0.f, 0.f, 0.f, 0.f};
            acc3[mi][nj] = (f32x4){0.f, 0.f, 0.f, 0.f};
        }

    // precompute frag-read LDS offsets (element units)
    int aoff[4], boff[2];
#pragma unroll
    for (int mi = 0; mi < 4; ++mi) {
        int m = wr * 64 + mi * 16 + lm;
        int g = m >> 1;
        aoff[mi] = g * 64 + (((lq + ((m & 1) << 2)) ^ (g & 7)) << 3);
    }
#pragma unroll
    for (int nj = 0; nj < 2; ++nj) {
        int n = wc * 32 + nj * 16 + lm;
        int g = n >> 1;
        boff[nj] = g * 64 + (((lq + ((n & 1) << 2)) ^ (g & 7)) << 3);
    }

    // prologue
#pragma unroll
    for (int i = 0; i < 2; ++i) async_ld16(xg[i], &Xs[0][(wave * 128 + i * 64) * 8]);
    async_ld16(w1g, &W1s[0][wave * 512]);
    async_ld16(w3g, &W3s[0][wave * 512]);

    const int NK = H / 32;
    for (int kk = 0; kk < NK; ++kk) {
        int cur = kk & 1;
        __syncthreads();
        if (kk + 1 < NK) {
            int nxt = cur ^ 1;
            int k1 = (kk + 1) * 32;
#pragma unroll
            for (int i = 0; i < 2; ++i) async_ld16(xg[i] + k1, &Xs[nxt][(wave * 128 + i * 64) * 8]);
            async_ld16(w1g + k1, &W1s[nxt][wave * 512]);
            async_ld16(w3g + k1, &W3s[nxt][wave * 512]);
        }
        bf16x8 af[4], b1[2], b3[2];
#pragma unroll
        for (int mi = 0; mi < 4; ++mi) af[mi] = *(const bf16x8*)&Xs[cur][aoff[mi]];
#pragma unroll
        for (int nj = 0; nj < 2; ++nj) {
            b1[nj] = *(const bf16x8*)&W1s[cur][boff[nj]];
            b3[nj] = *(const bf16x8*)&W3s[cur][boff[nj]];
        }
#pragma unroll
        for (int mi = 0; mi < 4; ++mi)
#pragma unroll
            for (int nj = 0; nj < 2; ++nj) {
                acc1[mi][nj] = __builtin_amdgcn_mfma_f32_16x16x32_bf16(af[mi], b1[nj], acc1[mi][nj], 0, 0, 0);
                acc3[mi][nj] = __builtin_amdgcn_mfma_f32_16x16x32_bf16(af[mi], b3[nj], acc3[mi][nj], 0, 0, 0);
            }
    }
#pragma unroll
    for (int mi = 0; mi < 4; ++mi) {
#pragma unroll
        for (int r = 0; r < 4; ++r) {
            int trow = t0 + wr * 64 + mi * 16 + lq * 4 + r;
            if (trow < cnt) {
                size_t base = (size_t)(beg + trow) * IDIM + n0 + wc * 32 + lm;
#pragma unroll
                for (int nj = 0; nj < 2; ++nj) {
                    float h1 = acc1[mi][nj][r];
                    float sg = h1 / (1.f + __expf(-h1));
                    act[base + nj * 16] = f2bf(sg * acc3[mi][nj][r]);
                }
            }
        }
    }
}

// ---------------- GEMM B: outp_bf16[pos,:] = act @ w2^T ----------------
// 128x64 tile, BK=32, dbuf 24KB LDS, XCD swizzle. FROZEN (R0/R5-verified).
__global__ __launch_bounds__(256, 5) void gemm_b_kernel(
    const unsigned short* __restrict__ act,
    const unsigned short* __restrict__ wb2,
    const int* __restrict__ offsets,
    unsigned short* __restrict__ outp)
{
    __shared__ unsigned short As[2][128 * 32];
    __shared__ unsigned short W2s[2][64 * 32];

    int bid = blockIdx.x;
    int xcd = bid & 7, s0 = bid >> 3;
    int yz = xcd * 32 + (s0 >> 4);
    int e = yz >> 4;
    int h0 = (yz & 15) * 64;
    int t0 = (s0 & 15) * 128;

    int beg = offsets[e];
    int cnt = offsets[e + 1] - beg;
    if (t0 >= cnt) return;

    int tid = threadIdx.x;
    int wave = tid >> 6, lane = tid & 63;

    const unsigned short* ag[2];
#pragma unroll
    for (int i = 0; i < 2; ++i) {
        int slot = wave * 128 + i * 64 + lane;
        int g = slot >> 3, sp = (slot & 7) ^ (g & 7);
        int row = g * 2 + (sp >> 2), c = sp & 3;
        int ar = beg + t0 + row; if (ar > NPAIR - 1) ar = NPAIR - 1;
        ag[i] = act + (size_t)ar * IDIM + c * 8;
    }
    const unsigned short* w2g;
    {
        int slot = wave * 64 + lane;
        int g = slot >> 3, sp = (slot & 7) ^ (g & 7);
        int row = g * 2 + (sp >> 2), c = sp & 3;
        w2g = wb2 + (size_t)e * H * IDIM + (size_t)(h0 + row) * IDIM + c * 8;
    }

    int wr = wave >> 1, wc = wave & 1;
    int lm = lane & 15, lq = lane >> 4;

    f32x4 acc[4][2];
#pragma unroll
    for (int mi = 0; mi < 4; ++mi)
#pragma unroll
        for (int nj = 0; nj < 2; ++nj) acc[mi][nj] = (f32x4){0.f, 0.f, 0.f, 0.f};

    int aoff[4], boff[2];
#pragma unroll
    for (int mi = 0; mi < 4; ++mi) {
        int m = wr * 64 + mi * 16 + lm;
        int g = m >> 1;
        aoff[mi] = g * 64 + (((lq + ((m & 1) << 2)) ^ (g & 7)) << 3);
    }
#pragma unroll
    for (int nj = 0; nj < 2; ++nj) {
        int n = wc * 32 + nj * 16 + lm;
        int g = n >> 1;
        boff[nj] = g * 64 + (((lq + ((n & 1) << 2)) ^ (g & 7)) << 3);
    }

#pragma unroll
    for (int i = 0; i < 2; ++i) async_ld16(ag[i], &As[0][(wave * 128 + i * 64) * 8]);
    async_ld16(w2g, &W2s[0][wave * 512]);

    const int NK = IDIM / 32;
    for (int kk = 0; kk < NK; ++kk) {
        int cur = kk & 1;
        __syncthreads();
        if (kk + 1 < NK) {
            int nxt = cur ^ 1;
            int k1 = (kk + 1) * 32;
#pragma unroll
            for (int i = 0; i < 2; ++i) async_ld16(ag[i] + k1, &As[nxt][(wave * 128 + i * 64) * 8]);
            async_ld16(w2g + k1, &W2s[nxt][wave * 512]);
        }
        bf16x8 af[4], bfr[2];
#pragma unroll
        for (int mi = 0; mi < 4; ++mi) af[mi] = *(const bf16x8*)&As[cur][aoff[mi]];
#pragma unroll
        for (int nj = 0; nj < 2; ++nj) bfr[nj] = *(const bf16x8*)&W2s[cur][boff[nj]];
#pragma unroll
        for (int mi = 0; mi < 4; ++mi)
#pragma unroll
            for (int nj = 0; nj < 2; ++nj)
                acc[mi][nj] = __builtin_amdgcn_mfma_f32_16x16x32_bf16(af[mi], bfr[nj], acc[mi][nj], 0, 0, 0);
    }
#pragma unroll
    for (int mi = 0; mi < 4; ++mi) {
#pragma unroll
        for (int r = 0; r < 4; ++r) {
            int trow = t0 + wr * 64 + mi * 16 + lq * 4 + r;
            if (trow < cnt) {
                unsigned short* orow = outp + (size_t)(beg + trow) * H + h0 + wc * 32 + lm;
#pragma unroll
                for (int nj = 0; nj < 2; ++nj) orow[nj * 16] = f2bf(acc[mi][nj][r]);
            }
        }
    }
}

// ---------------- Combine ----------------
__global__ __launch_bounds__(256) void combine_kernel(
    const unsigned short* __restrict__ outp, const int* __restrict__ inv_pos,
    const float* __restrict__ topk_w, float* __restrict__ out)
{
    int gid = blockIdx.x * 256 + threadIdx.x;
    int t = gid >> 8;
    int c4 = gid & 255;
    float4 a = make_float4(0.f, 0.f, 0.f, 0.f);
#pragma unroll
    for (int k = 0; k < TOPK; ++k) {
        int pos = inv_pos[t * TOPK + k];
        float w = topk_w[t * TOPK + k];
        ushort4 v = ((const ushort4*)(outp + (size_t)pos * H))[c4];
        a.x += w * bf2f(v.x); a.y += w * bf2f(v.y);
        a.z += w * bf2f(v.z); a.w += w * bf2f(v.w);
    }
    *(float4*)(out + (size_t)t * H + c4 * 4) = a;
}

extern "C" void kernel_launch(void* const* d_in, const int* in_sizes, int n_in,
                              void* d_out, int out_size, void* d_ws, size_t ws_size,
                              hipStream_t stream)
{
    const float* x  = (const float*)d_in[0];
    const float* gw = (const float*)d_in[1];
    const float* w1 = (const float*)d_in[2];
    const float* w3 = (const float*)d_in[3];
    const float* w2 = (const float*)d_in[4];
    float* out = (float*)d_out;

    char* ws = (char*)d_ws;
    int*   offsets    = (int*)(ws + 128);
    int*   topk_idx   = (int*)(ws + 1024);
    float* topk_w     = (float*)(ws + 33792);
    int*   pair_token = (int*)(ws + 66560);
    int*   inv_pos    = (int*)(ws + 99328);
    unsigned short* xb  = (unsigned short*)(ws + 262144);    // 4 MB
    unsigned short* wb1 = (unsigned short*)(ws + 8388608);   // 16 MB
    unsigned short* wb3 = (unsigned short*)(ws + 25165824);  // 16 MB
    unsigned short* wb2 = (unsigned short*)(ws + 41943040);  // 16 MB
    unsigned short* act = (unsigned short*)(ws + 58720256);  // 8 MB
    unsigned short* outp = (unsigned short*)(ws + 8388608);  // 16 MB, aliases wb1 (dead after gemm_a)

    router_kernel<<<T / 4, 256, 0, stream>>>(x, gw, topk_idx, topk_w, xb);

    // block 0 = route_build, blocks 1..4096 = cvt(w1,w3)
    cvtrb_kernel<<<1 + 2 * 2048, 256, 0, stream>>>(
        w1, w3, wb1, wb3, topk_idx, offsets, pair_token, inv_pos);

    // blocks 0..2047 = GEMM A (frozen), blocks 2048..4095 = cvt(w2) ride-along
    gemm_a_kernel<<<2 * 2048, 256, 0, stream>>>(
        xb, wb1, wb3, w2, wb2, offsets, pair_token, act);

    gemm_b_kernel<<<4096, 256, 0, stream>>>(act, wb2, offsets, outp);
    combine_kernel<<<(T * H / 4) / 256, 256, 0, stream>>>(outp, inv_pos, topk_w, out);
}